// Round 7
// baseline (216.277 us; speedup 1.0000x reference)
//
#include <hip/hip_runtime.h>
#include <math.h>
#include <stdint.h>

#define K_DIM 8192     // S*DIM
#define D_DIM 2048
#define M_ROWS 8192
#define N_W 32         // W columns (only 24 used in H)
#define NC 24
#define ROWS 16        // rows per block = one MFMA tile
#define THREADS 512
#define CHUNK_COLS 512                 // floats per row per chunk
#define NCHUNKS (K_DIM / CHUNK_COLS)   // 16
#define PADF 516                       // padded LDS row stride (floats)
#define PAD4 (PADF / 4)                // 129 float4

typedef short bf16x8 __attribute__((ext_vector_type(8)));
typedef float f32x4 __attribute__((ext_vector_type(4)));
union U32x4 { uint32_t u[4]; bf16x8 v; };

// wfrag layout (u16): [ks][tile(2)][hilo(2)][lane(64)][e(8)] -> 1 MB total.
// Fragment (ks,tile,hilo) is a contiguous 1KB block; lane l reads 16B at l*16
// -> wave reads 1KB coalesced; L2-resident for all blocks.
#define WFRAG_IDX(ks, tile, hilo) ((((ks) * 2 + (tile)) * 2 + (hilo)) * 64)

// ---------------------------------------------------------------------------
// Kernel 0: prepack W -> bf16 hi/lo B-fragments (once).
// k-map matches the A-fragment map: lane=((k&31)>>3)*16+(n&15), e=k&7.
// ---------------------------------------------------------------------------
__global__ __launch_bounds__(256) void mhc_prepack_kernel(
    const float* __restrict__ W, unsigned short* __restrict__ wfrag)
{
    const int idx = blockIdx.x * 256 + threadIdx.x;   // 0 .. 262143
    const int k = idx >> 5, n = idx & 31;
    const float w = W[(size_t)k * N_W + n];
    const uint32_t u = __float_as_uint(w);
    const float hif = __uint_as_float(u & 0xFFFF0000u);
    const uint32_t ur = __float_as_uint(w - hif);

    const int ks = k >> 5, kk = k & 31;
    const int lane = ((kk >> 3) << 4) | (n & 15);
    const int e = kk & 7;
    const int tile = n >> 4;
    unsigned short* p = wfrag + ((size_t)WFRAG_IDX(ks, tile, 0) + lane) * 8 + e;
    p[0]   = (unsigned short)(u >> 16);    // hi  (hilo stride = 64*8 = 512 u16)
    p[512] = (unsigned short)(ur >> 16);   // lo
}

// ---------------------------------------------------------------------------
// Kernel 1: H[m,0:24] = X@W[:,0:24] via MFMA, bf16 hi/lo split.
// Block = 512 thr (8 waves) owns a 16-row tile over FULL K (no atomics).
// Per 512-col chunk: coalesced global->reg (4 float4/thr), reg->LDS
// [16][516] padded tile (write conflict-free; A-frag b128 reads land at the
// 8-access/bank throughput floor), double-buffered, 1 barrier/chunk.
// Wave wv computes ksteps {2wv, 2wv+1} of the chunk's 16: per kstep a lane
// ds_reads 8 row-floats, converts to hi/lo bf16, loads 4 wfrag frags (L2),
// 6 MFMA. H = Xhi@Whi + Xlo@Whi + Xhi@Wlo.
// Epilogue: LDS-reduce 8 waves' partials; direct store (no atomics).
// C/D layout: D[row=(l>>4)*4+reg][col=l&15]  [HW-verified].
// ---------------------------------------------------------------------------
__global__ __launch_bounds__(THREADS, 4) void mhc_gemm_kernel(
    const float* __restrict__ X, const unsigned short* __restrict__ wfrag,
    float* __restrict__ Hsum)
{
    __shared__ __align__(16) float Xl[2][ROWS * PADF];   // 2 x 33,024 B
    __shared__ float Hpart[8][ROWS][NC];                 // 12,288 B
    const int t = threadIdx.x;
    const int l = t & 63;
    const int wv = t >> 6;
    const int rowbase = blockIdx.x * ROWS;

    f32x4 c0 = {0.f, 0.f, 0.f, 0.f};
    f32x4 c1 = {0.f, 0.f, 0.f, 0.f};
    const float4* __restrict__ Xg = reinterpret_cast<const float4*>(X);
    const bf16x8* __restrict__ wf = reinterpret_cast<const bf16x8*>(wfrag);

    float4 pf[4];
    auto LOADC = [&](int c) {
#pragma unroll
        for (int j = 0; j < 4; ++j) {
            const int F = j * THREADS + t;           // 0..2047
            const int row = F >> 7, slot = F & 127;
            pf[j] = Xg[(size_t)(rowbase + row) * (K_DIM / 4) + c * 128 + slot];
        }
    };
    auto WRITEC = [&](int b) {
        float4* dst = reinterpret_cast<float4*>(Xl[b]);
#pragma unroll
        for (int j = 0; j < 4; ++j) {
            const int F = j * THREADS + t;
            const int row = F >> 7, slot = F & 127;
            dst[row * PAD4 + slot] = pf[j];
        }
    };

    LOADC(0);
    WRITEC(0);
    __syncthreads();

    for (int c = 0; c < NCHUNKS; ++c) {
        if (c + 1 < NCHUNKS) LOADC(c + 1);
        const float* xt = Xl[c & 1];
#pragma unroll
        for (int u = 0; u < 2; ++u) {
            const int ksl = wv * 2 + u;              // kstep within chunk
            const int ks = c * 16 + ksl;             // global kstep
            const float* xp = xt + (l & 15) * PADF + ksl * 32 + ((l >> 4) << 3);
            const float4 xa = *reinterpret_cast<const float4*>(xp);
            const float4 xb = *reinterpret_cast<const float4*>(xp + 4);
            float xs[8];
            xs[0] = xa.x; xs[1] = xa.y; xs[2] = xa.z; xs[3] = xa.w;
            xs[4] = xb.x; xs[5] = xb.y; xs[6] = xb.z; xs[7] = xb.w;

            U32x4 ah, al;
#pragma unroll
            for (int p = 0; p < 4; ++p) {
                const uint32_t u0 = __float_as_uint(xs[2 * p]);
                const uint32_t u1 = __float_as_uint(xs[2 * p + 1]);
                const float h0 = __uint_as_float(u0 & 0xFFFF0000u);
                const float h1 = __uint_as_float(u1 & 0xFFFF0000u);
                const uint32_t r0 = __float_as_uint(xs[2 * p] - h0);
                const uint32_t r1 = __float_as_uint(xs[2 * p + 1] - h1);
                ah.u[p] = (u1 & 0xFFFF0000u) | (u0 >> 16);
                al.u[p] = (r1 & 0xFFFF0000u) | (r0 >> 16);
            }

            const bf16x8 bh0 = wf[WFRAG_IDX(ks, 0, 0) + l];
            const bf16x8 bl0 = wf[WFRAG_IDX(ks, 0, 1) + l];
            const bf16x8 bh1 = wf[WFRAG_IDX(ks, 1, 0) + l];
            const bf16x8 bl1 = wf[WFRAG_IDX(ks, 1, 1) + l];

            c0 = __builtin_amdgcn_mfma_f32_16x16x32_bf16(ah.v, bh0, c0, 0, 0, 0);
            c0 = __builtin_amdgcn_mfma_f32_16x16x32_bf16(al.v, bh0, c0, 0, 0, 0);
            c0 = __builtin_amdgcn_mfma_f32_16x16x32_bf16(ah.v, bl0, c0, 0, 0, 0);
            c1 = __builtin_amdgcn_mfma_f32_16x16x32_bf16(ah.v, bh1, c1, 0, 0, 0);
            c1 = __builtin_amdgcn_mfma_f32_16x16x32_bf16(al.v, bh1, c1, 0, 0, 0);
            c1 = __builtin_amdgcn_mfma_f32_16x16x32_bf16(ah.v, bl1, c1, 0, 0, 0);
        }
        if (c + 1 < NCHUNKS) WRITEC((c + 1) & 1);
        __syncthreads();
    }

    // ---- epilogue: stash partials, reduce across 8 waves, store H ----
#pragma unroll
    for (int r = 0; r < 4; ++r)
        Hpart[wv][((l >> 4) << 2) + r][l & 15] = c0[r];
    if ((l & 15) < 8) {
#pragma unroll
        for (int r = 0; r < 4; ++r)
            Hpart[wv][((l >> 4) << 2) + r][16 + (l & 15)] = c1[r];
    }
    __syncthreads();

    if (t < ROWS * NC) {
        const int row = t / NC, col = t % NC;
        float h = 0.f;
#pragma unroll
        for (int w = 0; w < 8; ++w) h += Hpart[w][row][col];
        Hsum[(size_t)(rowbase + row) * NC + col] = h;
    }
}

// ---------------------------------------------------------------------------
// Kernel 2: params (transform + sinkhorn) + apply. One block per row.
// ---------------------------------------------------------------------------
__global__ __launch_bounds__(256) void mhc_apply_kernel(
    const float* __restrict__ X, const float* __restrict__ Hsum,
    const float* __restrict__ ab, float* __restrict__ out)
{
    __shared__ float pbuf[NC];
    const int row = blockIdx.x;
    const int t = threadIdx.x;

    if (t < 64) {
        const int lane = t;
        const float pl = (lane < NC) ? Hsum[(size_t)row * NC + lane] : 0.f;
        const float bias  = (lane < NC) ? ab[lane] : 0.f;
        const float scale = ab[(lane < 16) ? 24 : ((lane < 20) ? 25 : 26)];

        float vout;
        if (lane < 16) {
            vout = __expf(fmaf(scale, pl, bias));                 // exp(a_res*H+b)
        } else {
            vout = fmaf(scale, 1.f / (1.f + __expf(-pl)), bias);  // a*sigmoid(H)+b
        }

        // Sinkhorn on lanes 0..15: lane = s*4 + i.
        float p = vout;
        for (int it = 0; it < 20; ++it) {
            float rs = p + __shfl_xor(p, 1);
            rs += __shfl_xor(rs, 2);
            p = p / rs;
            float cs = p + __shfl_xor(p, 4);
            cs += __shfl_xor(cs, 8);
            p = p / cs;
        }
        if (lane < NC) pbuf[lane] = (lane < 16) ? p : vout;
    }
    __syncthreads();

    float hres[4][4], hpre[4], hpos[4];
#pragma unroll
    for (int i = 0; i < 16; ++i) hres[i >> 2][i & 3] = pbuf[i];
#pragma unroll
    for (int i = 0; i < 4; ++i) hpre[i] = pbuf[16 + i];
#pragma unroll
    for (int i = 0; i < 4; ++i) hpos[i] = pbuf[20 + i];

    const float4* __restrict__ Xr =
        reinterpret_cast<const float4*>(X + (size_t)row * K_DIM);
    float4* __restrict__ Or = reinterpret_cast<float4*>(out + (size_t)row * K_DIM);

#pragma unroll
    for (int q = 0; q < 2; ++q) {
        const int pos = t + q * 256;          // float4 index within a 2048-seg
        float4 xq[4];
#pragma unroll
        for (int i = 0; i < 4; ++i) xq[i] = Xr[i * (D_DIM / 4) + pos];

        float y[4];
#pragma unroll
        for (int e = 0; e < 4; ++e) {
            float s = 0.f;
#pragma unroll
            for (int i = 0; i < 4; ++i)
                s = fmaf(hpre[i], reinterpret_cast<const float*>(&xq[i])[e], s);
            y[e] = s;
        }

#pragma unroll
        for (int s = 0; s < 4; ++s) {
            float4 o;
            float* oe = reinterpret_cast<float*>(&o);
#pragma unroll
            for (int e = 0; e < 4; ++e) {
                float v = hpos[s] * y[e];
#pragma unroll
                for (int i = 0; i < 4; ++i)
                    v = fmaf(hres[s][i], reinterpret_cast<const float*>(&xq[i])[e], v);
                oe[e] = v;
            }
            Or[s * (D_DIM / 4) + pos] = o;
        }
    }
}

extern "C" void kernel_launch(void* const* d_in, const int* in_sizes, int n_in,
                              void* d_out, int out_size, void* d_ws, size_t ws_size,
                              hipStream_t stream) {
    const float* X  = (const float*)d_in[0];
    const float* W  = (const float*)d_in[1];
    const float* ab = (const float*)d_in[2];
    float* out = (float*)d_out;
    unsigned short* wfrag = (unsigned short*)d_ws;          // 1,048,576 B
    float* Hsum = (float*)((char*)d_ws + 1048576);          // + 786,432 B

    mhc_prepack_kernel<<<(K_DIM * N_W) / 256, 256, 0, stream>>>(W, wfrag);
    mhc_gemm_kernel<<<M_ROWS / ROWS, THREADS, 0, stream>>>(X, wfrag, Hsum);
    mhc_apply_kernel<<<M_ROWS, 256, 0, stream>>>(X, Hsum, ab, out);
}